// Round 1
// baseline (418.599 us; speedup 1.0000x reference)
//
#include <hip/hip_runtime.h>
#include <hip/hip_bf16.h>
#include <stdint.h>

typedef __attribute__((ext_vector_type(8))) short short8;
typedef __attribute__((ext_vector_type(16))) float f32x16;

#define CD 256   // channels
#define HD 512   // hidden

// ---------- helpers ----------
static __device__ __forceinline__ unsigned short f2bf(float f) {
    union { float f; unsigned int u; } cv; cv.f = f;
    unsigned int u = cv.u;
    unsigned int r = u + 0x7FFFu + ((u >> 16) & 1u);   // round-to-nearest-even
    return (unsigned short)(r >> 16);
}

// ---------- kernel 1: Wt fp32 -> bf16 (H*C = 131072 elems, 8/thread) ----------
__global__ void cvt_wt_kernel(const float* __restrict__ wt, unsigned short* __restrict__ out) {
    int t = blockIdx.x * blockDim.x + threadIdx.x;     // 16384 threads
    const float4* p = (const float4*)wt;
    float4 f0 = p[t * 2], f1 = p[t * 2 + 1];
    unsigned int r0 = (unsigned int)f2bf(f0.x) | ((unsigned int)f2bf(f0.y) << 16);
    unsigned int r1 = (unsigned int)f2bf(f0.z) | ((unsigned int)f2bf(f0.w) << 16);
    unsigned int r2 = (unsigned int)f2bf(f1.x) | ((unsigned int)f2bf(f1.y) << 16);
    unsigned int r3 = (unsigned int)f2bf(f1.z) | ((unsigned int)f2bf(f1.w) << 16);
    uint4 v; v.x = r0; v.y = r1; v.z = r2; v.w = r3;
    ((uint4*)out)[t] = v;
}

// ---------- kernel 2: batch (int64 OR int32) -> int32 ----------
__global__ void cvt_batch_kernel(const void* __restrict__ batch, int* __restrict__ out, int n) {
    const long long* p64 = (const long long*)batch;
    const int* p32 = (const int*)batch;
    // int64 data: value in [0,1024). int32 data: reads a pair (lo | hi<<32) with hi>0 -> huge.
    bool is64 = ((unsigned long long)p64[n / 2 - 1]) < (1ull << 20);
    for (int i = blockIdx.x * blockDim.x + threadIdx.x; i < n; i += gridDim.x * blockDim.x)
        out[i] = is64 ? (int)p64[i] : p32[i];
}

// ---------- kernel 3: gate logits via bf16 MFMA ----------
// per block: 256 rows (4 waves x 64), full H=512 looped in 128-h LDS chunks.
// logits[i] = sum_h softplus(x[i,:] . Wt[h,:] + bt[h]) * Wg[h] + bg
__global__ __launch_bounds__(256, 2) void gate_kernel(
    const float* __restrict__ x, const unsigned short* __restrict__ wtb,
    const float* __restrict__ bt, const float* __restrict__ wg,
    const float* __restrict__ bg, float* __restrict__ logits, int n)
{
    __shared__ uint4 lds[4096];                       // 64 KB: 128 h-rows x 256 cols bf16
    const int tid = threadIdx.x;
    const int lane = tid & 63;
    const int wid = tid >> 6;
    const int l31 = lane & 31;
    const int g = lane >> 5;                          // k-group 0/1
    const long rowbase = (long)blockIdx.x * 256 + wid * 64;

    // A fragments: rows rowbase + t*32 + l31, k = kt*16 + g*8 + j  (8 consecutive floats)
    short8 a[2][16];
#pragma unroll
    for (int t = 0; t < 2; ++t) {
        const long row = rowbase + t * 32 + l31;
        const bool ok = row < (long)n;
        const float4* xr = (const float4*)x + row * 64 + g * 2;
#pragma unroll
        for (int kt = 0; kt < 16; ++kt) {
            float4 f0, f1;
            if (ok) { f0 = xr[kt * 4]; f1 = xr[kt * 4 + 1]; }
            else    { f0 = make_float4(0.f,0.f,0.f,0.f); f1 = make_float4(0.f,0.f,0.f,0.f); }
            short8 v;
            v[0] = (short)f2bf(f0.x); v[1] = (short)f2bf(f0.y);
            v[2] = (short)f2bf(f0.z); v[3] = (short)f2bf(f0.w);
            v[4] = (short)f2bf(f1.x); v[5] = (short)f2bf(f1.y);
            v[6] = (short)f2bf(f1.z); v[7] = (short)f2bf(f1.w);
            a[t][kt] = v;
        }
    }

    float lp0[16], lp1[16];
#pragma unroll
    for (int r = 0; r < 16; ++r) { lp0[r] = 0.f; lp1[r] = 0.f; }

    const uint4* wtg = (const uint4*)wtb;
    const short8* lp8 = (const short8*)lds;

    for (int hc = 0; hc < 4; ++hc) {
        __syncthreads();
        // stage 128-h chunk, XOR-swizzled: granule gi -> gi ^ ((gi>>5)&15)
#pragma unroll
        for (int it = 0; it < 16; ++it) {
            int gi = it * 256 + tid;
            uint4 v = wtg[hc * 4096 + gi];
            lds[gi ^ ((gi >> 5) & 15)] = v;
        }
        __syncthreads();
        for (int ht = 0; ht < 4; ++ht) {
            const int hl = ht * 32 + l31;             // h row within chunk
            f32x16 acc0, acc1;
#pragma unroll
            for (int r = 0; r < 16; ++r) { acc0[r] = 0.f; acc1[r] = 0.f; }
            const int swz = hl & 15;
            const int rowg = hl * 32 + g;             // granule base: B frag k-chunk
#pragma unroll
            for (int kt = 0; kt < 16; ++kt) {
                short8 b = lp8[(rowg + kt * 2) ^ swz];
                acc0 = __builtin_amdgcn_mfma_f32_32x32x16_bf16(a[0][kt], b, acc0, 0, 0, 0);
                acc1 = __builtin_amdgcn_mfma_f32_32x32x16_bf16(a[1][kt], b, acc1, 0, 0, 0);
            }
            const int h = hc * 128 + hl;
            const float btv = bt[h];
            const float wgv = wg[h];
#pragma unroll
            for (int r = 0; r < 16; ++r) {
                float v0 = acc0[r] + btv;
                float v1 = acc1[r] + btv;
                float sp0 = fmaxf(v0, 0.f) + __logf(1.f + __expf(-fabsf(v0)));
                float sp1 = fmaxf(v1, 0.f) + __logf(1.f + __expf(-fabsf(v1)));
                lp0[r] = fmaf(sp0, wgv, lp0[r]);
                lp1[r] = fmaf(sp1, wgv, lp1[r]);
            }
        }
    }

    // reduce over the 32 h-columns (lanes within each 32-lane half)
#pragma unroll
    for (int r = 0; r < 16; ++r) {
        float v0 = lp0[r], v1 = lp1[r];
        v0 += __shfl_xor(v0, 1);  v1 += __shfl_xor(v1, 1);
        v0 += __shfl_xor(v0, 2);  v1 += __shfl_xor(v1, 2);
        v0 += __shfl_xor(v0, 4);  v1 += __shfl_xor(v1, 4);
        v0 += __shfl_xor(v0, 8);  v1 += __shfl_xor(v1, 8);
        v0 += __shfl_xor(v0, 16); v1 += __shfl_xor(v1, 16);
        lp0[r] = v0; lp1[r] = v1;
    }
    if (l31 == 0) {
        const float bgv = bg[0];
#pragma unroll
        for (int r = 0; r < 16; ++r) {
            long row0 = rowbase + 4 * g + (r & 3) + 8 * (r >> 2);   // C/D layout (m74/m101)
            if (row0 < n) logits[row0] = lp0[r] + bgv;
            long row1 = row0 + 32;
            if (row1 < n) logits[row1] = lp1[r] + bgv;
        }
    }
}

// ---------- kernel 4: per-segment stats ----------
static __device__ __forceinline__ int lower_bound(const int* __restrict__ a, int n, int v) {
    int lo = 0, hi = n;
    while (lo < hi) { int mid = (lo + hi) >> 1; if (a[mid] < v) lo = mid + 1; else hi = mid; }
    return lo;
}

__global__ void segstats_kernel(const int* __restrict__ batch, const float* __restrict__ logits,
    float* __restrict__ segmax, float* __restrict__ segrs, float* __restrict__ seginv,
    int* __restrict__ segstart, int* __restrict__ segcnt, int n)
{
    const int b = blockIdx.x;
    __shared__ int sh_se[2];
    __shared__ float sh_red[4];
    const int tid = threadIdx.x;
    if (tid == 0) {
        sh_se[0] = lower_bound(batch, n, b);
        sh_se[1] = lower_bound(batch, n, b + 1);
    }
    __syncthreads();
    const int start = sh_se[0], end = sh_se[1];
    float m = -3.4e38f;
    for (int i = start + tid; i < end; i += 256) m = fmaxf(m, logits[i]);
#pragma unroll
    for (int mk = 1; mk <= 32; mk <<= 1) m = fmaxf(m, __shfl_xor(m, mk));
    if ((tid & 63) == 0) sh_red[tid >> 6] = m;
    __syncthreads();
    m = fmaxf(fmaxf(sh_red[0], sh_red[1]), fmaxf(sh_red[2], sh_red[3]));
    float s = 0.f;
    for (int i = start + tid; i < end; i += 256) s += __expf(logits[i] - m);
#pragma unroll
    for (int mk = 1; mk <= 32; mk <<= 1) s += __shfl_xor(s, mk);
    __syncthreads();
    if ((tid & 63) == 0) sh_red[tid >> 6] = s;
    __syncthreads();
    if (tid == 0) {
        s = sh_red[0] + sh_red[1] + sh_red[2] + sh_red[3];
        const int cnt = end - start;
        segmax[b] = m;
        segrs[b] = (s > 0.f) ? (1.f / s) : 0.f;
        seginv[b] = 1.f / (float)((cnt > 0) ? cnt : 1);
        segstart[b] = start;
        segcnt[b] = cnt;
    }
}

// ---------- kernel 5: fused per-node weight w' = attn + 1/cnt ----------
__global__ void weights_kernel(const int* __restrict__ batch, const float* __restrict__ logits,
    const float* __restrict__ segmax, const float* __restrict__ segrs,
    const float* __restrict__ seginv, float* __restrict__ wout, int n)
{
    for (int i = blockIdx.x * blockDim.x + threadIdx.x; i < n; i += gridDim.x * blockDim.x) {
        int b = batch[i];
        wout[i] = __expf(logits[i] - segmax[b]) * segrs[b] + seginv[b];
    }
}

// ---------- kernel 6: pooled output out[b,c] = sum_i w'[i] * x[i,c] ----------
__global__ __launch_bounds__(256) void pool_kernel(const float* __restrict__ x,
    const float* __restrict__ w, const int* __restrict__ segstart,
    const int* __restrict__ segcnt, float* __restrict__ out)
{
    const int b = blockIdx.x;
    const int c = threadIdx.x;
    const int start = segstart[b];
    const int cnt = segcnt[b];
    const float* xp = x + (size_t)start * CD + c;
    const float* wp = w + start;
    float acc = 0.f;
    int i = 0;
    for (; i + 8 <= cnt; i += 8) {
        float w0 = wp[i], w1 = wp[i+1], w2 = wp[i+2], w3 = wp[i+3];
        float w4 = wp[i+4], w5 = wp[i+5], w6 = wp[i+6], w7 = wp[i+7];
        float x0 = xp[(size_t)(i+0)*CD], x1 = xp[(size_t)(i+1)*CD];
        float x2 = xp[(size_t)(i+2)*CD], x3 = xp[(size_t)(i+3)*CD];
        float x4 = xp[(size_t)(i+4)*CD], x5 = xp[(size_t)(i+5)*CD];
        float x6 = xp[(size_t)(i+6)*CD], x7 = xp[(size_t)(i+7)*CD];
        acc = fmaf(w0,x0,fmaf(w1,x1,fmaf(w2,x2,fmaf(w3,x3,acc))));
        acc = fmaf(w4,x4,fmaf(w5,x5,fmaf(w6,x6,fmaf(w7,x7,acc))));
    }
    for (; i < cnt; ++i) acc = fmaf(wp[i], xp[(size_t)i*CD], acc);
    out[(size_t)b * CD + c] = acc;
}

// ---------- launcher ----------
extern "C" void kernel_launch(void* const* d_in, const int* in_sizes, int n_in,
                              void* d_out, int out_size, void* d_ws, size_t ws_size,
                              hipStream_t stream)
{
    const float* x  = (const float*)d_in[0];
    const void*  batch = d_in[1];
    const float* Wt = (const float*)d_in[3];
    const float* bt = (const float*)d_in[4];
    const float* Wg = (const float*)d_in[5];
    const float* bg = (const float*)d_in[6];
    float* out = (float*)d_out;
    const int n = in_sizes[1];            // 400000
    const int nseg = out_size / CD;       // 1024

    char* ws = (char*)d_ws;
    size_t off = 0;
    unsigned short* wtb = (unsigned short*)(ws + off); off += (size_t)HD * CD * 2;  // 262144
    float* logits = (float*)(ws + off); off += (size_t)n * 4;
    float* wnode  = (float*)(ws + off); off += (size_t)n * 4;
    float* segmax = (float*)(ws + off); off += (size_t)nseg * 4;
    float* segrs  = (float*)(ws + off); off += (size_t)nseg * 4;
    float* seginv = (float*)(ws + off); off += (size_t)nseg * 4;
    int* segstart = (int*)(ws + off);   off += (size_t)nseg * 4;
    int* segcnt   = (int*)(ws + off);   off += (size_t)nseg * 4;
    int* batch32  = (int*)(ws + off);   off += (size_t)n * 4;

    hipLaunchKernelGGL(cvt_wt_kernel, dim3((HD * CD / 8) / 256), dim3(256), 0, stream, Wt, wtb);
    hipLaunchKernelGGL(cvt_batch_kernel, dim3(512), dim3(256), 0, stream, batch, batch32, n);
    hipLaunchKernelGGL(gate_kernel, dim3((n + 255) / 256), dim3(256), 0, stream,
                       x, wtb, bt, Wg, bg, logits, n);
    hipLaunchKernelGGL(segstats_kernel, dim3(nseg), dim3(256), 0, stream,
                       batch32, logits, segmax, segrs, seginv, segstart, segcnt, n);
    hipLaunchKernelGGL(weights_kernel, dim3(512), dim3(256), 0, stream,
                       batch32, logits, segmax, segrs, seginv, wnode, n);
    hipLaunchKernelGGL(pool_kernel, dim3(nseg), dim3(256), 0, stream,
                       x, wnode, segstart, segcnt, out);
}